// Round 8
// baseline (3144.756 us; speedup 1.0000x reference)
//
#include <hip/hip_runtime.h>

// VanillaRNN: h_{t+1} = tanh(h_t + x_t) @ W^T ; out = [h_0..h_T]
// B=32, T=2048, N=512, fp32 in/out.
//
// One 512-thread WG per batch row (32 WGs, sync-free across WGs; the serial
// T-chain runs inside the WG). W is held CU-RESIDENT as fp16 k-pairs in
// three tiers (spill-safe split, peak live VGPR ~236/256):
//   40/64 pair-quads per lane in VGPRs (160 regs),
//   10/64 in LDS    (80 KiB; ~960 cy/step of LDS pipe),
//   14/64 streamed  (112 KiB/step from L2; ~1950 cy at ~60 B/cy/CU),
// so RF / LDS / VMEM run in parallel above the VALU dot2 floor (~1150 cy).
// v_t is fp16 in double-buffered LDS (wave-uniform broadcast reads);
// per-wave k-slice partials reduce via conflict-free pacc[w][i][l].
// 2 barriers/step. Projected ~2000-2200 cy/step -> ~1.8 ms total.
//
// R6: PACKED template switch — ws_size >= 512 KiB uses the pre-packed fast
// path; smaller workspaces fall back to zero-scratch inline fp32->fp16
// conversion (~2x step) instead of faulting. Host picks from ws_size
// (constant per session -> graph-capture safe).
// R7: resubmitted unchanged (8th consecutive GPU-acquisition timeout; all
// static audits closed, remaining questions are empirical-only).

#define RNN_B 32
#define RNN_T 2048
#define RNN_N 512

typedef __attribute__((ext_vector_type(2))) _Float16 half2_t;
union H2U { half2_t h2; unsigned int u; };
union HU  { _Float16 h; unsigned short u; };

__device__ __forceinline__ float fdot2f(unsigned int a, unsigned int b, float c) {
#if __has_builtin(__builtin_amdgcn_fdot2)
  H2U ua, ub; ua.u = a; ub.u = b;
  return __builtin_amdgcn_fdot2(ua.h2, ub.h2, c, false);
#else
  H2U ua, ub; ua.u = a; ub.u = b;
  return c + (float)ua.h2.x * (float)ub.h2.x + (float)ua.h2.y * (float)ub.h2.y;
#endif
}

// tanh(x) = 1 - 2/(e^{2x}+1); self-saturating at +-1 for large |x| (inf-safe).
__device__ __forceinline__ float fast_tanh(float x) {
#if __has_builtin(__builtin_amdgcn_exp2f) && __has_builtin(__builtin_amdgcn_rcpf)
  float e = __builtin_amdgcn_exp2f(x * 2.885390082f);  // e^{2x}
  return 1.0f - 2.0f * __builtin_amdgcn_rcpf(e + 1.0f);
#else
  return tanhf(x);
#endif
}

// ---------------------------------------------------------------------------
// Pack W (row-major W[j][k], out j, in k) into quad layout WpQ:
//   flat idx = ((w*64 + Q)*64 + l)*4 + s   (w:wave/k-slice, Q:quad, l:lane)
//   Q = i*8 + kc*2 + u4  (i: col-block, kc: k-chunk, u4: half-chunk)
//   element = half2( W[col][2*kp], W[col][2*kp+1] )
//   col = i*64 + l ; kp = w*32 + kc*8 + u4*4 + s
// Tiers: Q<40 VGPR-resident; 40<=Q<50 LDS-resident (slot m=Q-40); Q>=50 streamed.
// ---------------------------------------------------------------------------
__global__ __launch_bounds__(256) void pack_w(const float* __restrict__ W,
                                              unsigned int* __restrict__ WpQ) {
  int idx = blockIdx.x * 256 + threadIdx.x;   // 0 .. 131071
  int s  = idx & 3;
  int l  = (idx >> 2) & 63;
  int Q  = (idx >> 8) & 63;
  int w  = idx >> 14;
  int i  = Q >> 3, kc = (Q >> 1) & 3, u4 = Q & 1;
  int col = i * 64 + l;
  int kp  = w * 32 + kc * 8 + u4 * 4 + s;
  H2U c;
  c.h2.x = (_Float16)W[col * RNN_N + 2 * kp];
  c.h2.y = (_Float16)W[col * RNN_N + 2 * kp + 1];
  WpQ[idx] = c.u;
}

#define DOTQ(ai, S, V)                          \
  do {                                          \
    acc[ai] = fdot2f((S).x, (V).x, acc[ai]);    \
    acc[ai] = fdot2f((S).y, (V).y, acc[ai]);    \
    acc[ai] = fdot2f((S).z, (V).z, acc[ai]);    \
    acc[ai] = fdot2f((S).w, (V).w, acc[ai]);    \
  } while (0)

// ---------------------------------------------------------------------------
template <bool PACKED>
__global__ __launch_bounds__(512, 2) void rnn_kernel(const float* __restrict__ X,
                                                     const float* __restrict__ H0,
                                                     const unsigned int* __restrict__ WpQ,
                                                     const float* __restrict__ W,
                                                     float* __restrict__ out) {
  __shared__ uint4 ldsw[8 * 10 * 64];                                    // 80 KiB: [w][m][l]
  __shared__ unsigned short vbuf[2][RNN_N] __attribute__((aligned(16))); // 2 KiB
  __shared__ float pacc[8][8][64];                                       // 16 KiB: [w][i][l]

  const int b   = blockIdx.x;
  const int tid = threadIdx.x;
  const int w   = tid >> 6;
  const int l   = tid & 63;

  const float* __restrict__ Xb = X + (size_t)b * RNN_T * RNN_N;
  float* __restrict__ outb     = out + (size_t)b * (RNN_T + 1) * RNN_N;

  // Per-lane quad base (packed path): quad Q lives at pb[Q*64].
  const uint4* __restrict__ pb = (const uint4*)WpQ + (size_t)w * 4096 + l;

  // Fetch quad Q for this (w,l): packed uint4, or fp32->fp16 inline convert.
  auto loadq = [&](int Q) -> uint4 {
    if constexpr (PACKED) {
      return pb[Q * 64];
    } else {
      int i = Q >> 3, kc = (Q >> 1) & 3, u4 = Q & 1;
      int col = i * 64 + l;
      const float* src = W + (size_t)col * RNN_N + 2 * (w * 32 + kc * 8 + u4 * 4);
      float4 f0 = *(const float4*)src;
      float4 f1 = *(const float4*)(src + 4);
      H2U p0, p1, p2, p3;
      p0.h2.x = (_Float16)f0.x; p0.h2.y = (_Float16)f0.y;
      p1.h2.x = (_Float16)f0.z; p1.h2.y = (_Float16)f0.w;
      p2.h2.x = (_Float16)f1.x; p2.h2.y = (_Float16)f1.y;
      p3.h2.x = (_Float16)f1.z; p3.h2.y = (_Float16)f1.w;
      return make_uint4(p0.u, p1.u, p2.u, p3.u);
    }
  };

  // --- Prologue: VGPR-resident W (quads 0..39) ---
  uint4 wq[40];
  #pragma unroll
  for (int n = 0; n < 40; ++n) wq[n] = loadq(n);
  // LDS-resident W (quads 40..49) at slot m = Q-40.
  #pragma unroll
  for (int m = 0; m < 10; ++m) ldsw[(w * 10 + m) * 64 + l] = loadq(40 + m);

  // v_0 = tanh(h_0 + x_0); emit h_0.  (tid == column j; 512 threads == N)
  {
    float h0 = H0[b * RNN_N + tid];
    outb[tid] = h0;
    HU c; c.h = (_Float16)fast_tanh(h0 + Xb[tid]);
    vbuf[0][tid] = c.u;
  }
  __syncthreads();

  for (int t = 0; t < RNN_T; ++t) {
    const int buf = t & 1;

    // Stream group A (consumed in kc0/kc1): Q56,57 (kc0 i7); Q50,51 (kc1 i6);
    // Q58,59 (kc1 i7).
    uint4 sA0 = loadq(56), sA1 = loadq(57);
    uint4 sA2 = loadq(50), sA3 = loadq(51);
    uint4 sA4 = loadq(58), sA5 = loadq(59);

    // x_{t+1} for the upcoming reduce (in flight during the whole matvec).
    float xv = 0.0f;
    if (t + 1 < RNN_T) xv = Xb[(size_t)(t + 1) * RNN_N + tid];

    float acc[8] = {0.f, 0.f, 0.f, 0.f, 0.f, 0.f, 0.f, 0.f};
    const uint4* __restrict__ vb4 = (const uint4*)&vbuf[buf][0];

    // ---- kc = 0 ----  (v pairs w*32+0..7 ; LDS m0,m1 (i5) m8,m9 (i6))
    {
      uint4 vq0 = vb4[w * 8 + 0], vq1 = vb4[w * 8 + 1];   // wave-uniform: broadcast
      uint4 wl0 = ldsw[(w * 10 + 0) * 64 + l], wl1 = ldsw[(w * 10 + 1) * 64 + l];
      uint4 wl2 = ldsw[(w * 10 + 8) * 64 + l], wl3 = ldsw[(w * 10 + 9) * 64 + l];
      DOTQ(0, wq[0], vq0);  DOTQ(0, wq[1], vq1);
      DOTQ(1, wq[8], vq0);  DOTQ(1, wq[9], vq1);
      DOTQ(2, wq[16], vq0); DOTQ(2, wq[17], vq1);
      DOTQ(3, wq[24], vq0); DOTQ(3, wq[25], vq1);
      DOTQ(4, wq[32], vq0); DOTQ(4, wq[33], vq1);
      DOTQ(5, wl0, vq0);    DOTQ(5, wl1, vq1);    // Q40,41
      DOTQ(6, wl2, vq0);    DOTQ(6, wl3, vq1);    // Q48,49
      DOTQ(7, sA0, vq0);    DOTQ(7, sA1, vq1);    // Q56,57
    }
    // Stream group B (for kc2): Q52,53 (i6), Q60,61 (i7)
    uint4 sB0 = loadq(52), sB1 = loadq(53), sB2 = loadq(60), sB3 = loadq(61);

    // ---- kc = 1 ----  (v pairs +8..15 ; LDS m2,m3 (i5))
    {
      uint4 vq0 = vb4[w * 8 + 2], vq1 = vb4[w * 8 + 3];
      uint4 wl0 = ldsw[(w * 10 + 2) * 64 + l], wl1 = ldsw[(w * 10 + 3) * 64 + l];
      DOTQ(0, wq[2], vq0);  DOTQ(0, wq[3], vq1);
      DOTQ(1, wq[10], vq0); DOTQ(1, wq[11], vq1);
      DOTQ(2, wq[18], vq0); DOTQ(2, wq[19], vq1);
      DOTQ(3, wq[26], vq0); DOTQ(3, wq[27], vq1);
      DOTQ(4, wq[34], vq0); DOTQ(4, wq[35], vq1);
      DOTQ(5, wl0, vq0);    DOTQ(5, wl1, vq1);    // Q42,43
      DOTQ(6, sA2, vq0);    DOTQ(6, sA3, vq1);    // Q50,51
      DOTQ(7, sA4, vq0);    DOTQ(7, sA5, vq1);    // Q58,59
    }
    // Stream group C (for kc3): Q54,55 (i6), Q62,63 (i7)
    uint4 sC0 = loadq(54), sC1 = loadq(55), sC2 = loadq(62), sC3 = loadq(63);

    // ---- kc = 2 ----  (v pairs +16..23 ; LDS m4,m5 (i5))
    {
      uint4 vq0 = vb4[w * 8 + 4], vq1 = vb4[w * 8 + 5];
      uint4 wl0 = ldsw[(w * 10 + 4) * 64 + l], wl1 = ldsw[(w * 10 + 5) * 64 + l];
      DOTQ(0, wq[4], vq0);  DOTQ(0, wq[5], vq1);
      DOTQ(1, wq[12], vq0); DOTQ(1, wq[13], vq1);
      DOTQ(2, wq[20], vq0); DOTQ(2, wq[21], vq1);
      DOTQ(3, wq[28], vq0); DOTQ(3, wq[29], vq1);
      DOTQ(4, wq[36], vq0); DOTQ(4, wq[37], vq1);
      DOTQ(5, wl0, vq0);    DOTQ(5, wl1, vq1);    // Q44,45
      DOTQ(6, sB0, vq0);    DOTQ(6, sB1, vq1);    // Q52,53
      DOTQ(7, sB2, vq0);    DOTQ(7, sB3, vq1);    // Q60,61
    }

    // ---- kc = 3 ----  (v pairs +24..31 ; LDS m6,m7 (i5))
    {
      uint4 vq0 = vb4[w * 8 + 6], vq1 = vb4[w * 8 + 7];
      uint4 wl0 = ldsw[(w * 10 + 6) * 64 + l], wl1 = ldsw[(w * 10 + 7) * 64 + l];
      DOTQ(0, wq[6], vq0);  DOTQ(0, wq[7], vq1);
      DOTQ(1, wq[14], vq0); DOTQ(1, wq[15], vq1);
      DOTQ(2, wq[22], vq0); DOTQ(2, wq[23], vq1);
      DOTQ(3, wq[30], vq0); DOTQ(3, wq[31], vq1);
      DOTQ(4, wq[38], vq0); DOTQ(4, wq[39], vq1);
      DOTQ(5, wl0, vq0);    DOTQ(5, wl1, vq1);    // Q46,47
      DOTQ(6, sC0, vq0);    DOTQ(6, sC1, vq1);    // Q54,55
      DOTQ(7, sC2, vq0);    DOTQ(7, sC3, vq1);    // Q62,63
    }

    // Per-wave partials -> pacc[w][i][l]  (stride-1 in lane: conflict-free)
    #pragma unroll
    for (int i = 0; i < 8; ++i) pacc[w][i][l] = acc[i];
    __syncthreads();

    // Reduce: thread tid owns column j = tid = w*64 + l; reads pacc[ww][w][l],
    // ww=0..7 -- stride-1 in lane, conflict-free.
    {
      float p0 = pacc[0][w][l], p1 = pacc[1][w][l];
      float p2 = pacc[2][w][l], p3 = pacc[3][w][l];
      float p4 = pacc[4][w][l], p5 = pacc[5][w][l];
      float p6 = pacc[6][w][l], p7 = pacc[7][w][l];
      float s = ((p0 + p1) + (p2 + p3)) + ((p4 + p5) + (p6 + p7));
      outb[(size_t)(t + 1) * RNN_N + tid] = s;
      if (t + 1 < RNN_T) {
        HU c; c.h = (_Float16)fast_tanh(s + xv);
        vbuf[buf ^ 1][tid] = c.u;
      }
    }
    __syncthreads();
  }
}

// ---------------------------------------------------------------------------
extern "C" void kernel_launch(void* const* d_in, const int* in_sizes, int n_in,
                              void* d_out, int out_size, void* d_ws, size_t ws_size,
                              hipStream_t stream) {
  const float* X  = (const float*)d_in[0];   // (B, T, N) fp32
  const float* H0 = (const float*)d_in[1];   // (B, N)    fp32
  const float* W  = (const float*)d_in[2];   // (N, N)    fp32
  float* out      = (float*)d_out;           // (B, T+1, N) fp32

  if (ws_size >= (size_t)(512 * 1024)) {
    unsigned int* WpQ = (unsigned int*)d_ws;  // 131072 uints = 512 KiB scratch
    pack_w<<<dim3(512), dim3(256), 0, stream>>>(W, WpQ);
    rnn_kernel<true><<<dim3(RNN_B), dim3(512), 0, stream>>>(X, H0, WpQ, W, out);
  } else {
    // Zero-scratch fallback: convert W tiers inline from fp32 (slower but safe).
    rnn_kernel<false><<<dim3(RNN_B), dim3(512), 0, stream>>>(X, H0, nullptr, W, out);
  }
}